// Round 6
// baseline (83.982 us; speedup 1.0000x reference)
//
#include <hip/hip_runtime.h>
#include <hip/hip_fp16.h>
#include <cmath>

// Radon backprojection, three-phase, packed-fp16 LDS gather.
//
// R5 post-mortem: all gather variants stuck at ~40 us because the per-CU
// LDS/L1 pipes are ISSUE-bound: ~9 memory instructions per pixel-angle.
// R6: prepack kernel builds, per (angle, i), a 16B entry =
//   {half2(v0,v1) for batch0..3}  (v0=sino[b,a,i], v1=sino[b,a,i+1])
// so the main kernel's gather is ONE ds_read_b128 per pixel-angle.
// Staging: global_load_lds width=16 (contiguous entries in lane order ->
// legal wave-uniform-base + lane*16 layout). Trig via uniform s_load.

#define ACHUNKS 8
#define MAXPE   512

__device__ __forceinline__ void stage_pe(const uint4* __restrict__ g,
                                         uint4* l, int PE, int tid)
{
    // PE is a multiple of 64; each step covers whole waves.
    for (int e = tid; e < PE; e += 256) {
        const int wb = e & ~63;  // wave-uniform base entry
        // Generic->LDS offset: shared aperture is 4GB-aligned, low 32 bits
        // of a generic shared pointer are the LDS byte offset.
        uint32_t lds_off = (uint32_t)(uintptr_t)(l + wb);
        __builtin_amdgcn_global_load_lds(
            (const __attribute__((address_space(1))) uint32_t*)(g + e),
            (__attribute__((address_space(3))) uint32_t*)(uintptr_t)lds_off,
            16, 0, 0);
    }
}

__global__ __launch_bounds__(256) void radon_pack(
    const float* __restrict__ sino,
    const float* __restrict__ thetas,
    const float* __restrict__ positions,
    uint4* __restrict__ packed,        // [A][PE]
    float2* __restrict__ trig,         // [A+1]; trig[A].x = q0
    int A, int P, int PE, int bstride)
{
    const int idx = blockIdx.x * 256 + threadIdx.x;
    const int a = idx / PE;
    const int i = idx - a * PE;
    if (a >= A) return;

    const float p0     = positions[0];
    const float inv_dp = 1.0f / (positions[1] - p0);
    if (i == 0) {
        float th = thetas[a];
        trig[a] = make_float2(cosf(th) * inv_dp, sinf(th) * inv_dp);
        if (a == 0) trig[A] = make_float2(-p0 * inv_dp, 0.0f);
    }

    const int i0 = min(i, P - 1);
    const int i1 = min(i + 1, P - 1);
    const float* s = sino + (size_t)a * P;

    uint4 e;
    unsigned* ep = (unsigned*)&e;
#pragma unroll
    for (int b = 0; b < 4; ++b) {
        const float* sb = s + (size_t)b * bstride;
        __half2 h = __floats2half2_rn(sb[i0], sb[i1]);  // lo=v0, hi=v1
        ep[b] = *(const unsigned*)&h;
    }
    packed[(size_t)a * PE + i] = e;
}

__global__ __launch_bounds__(256) void radon_partial_pk(
    const uint4* __restrict__ packed,  // [A][PE]
    const float2* __restrict__ trig,   // [A+1]
    float* __restrict__ part,          // [ACHUNKS][4][nn]
    int A, int P, int PE, int N, int chunk)
{
    __shared__ uint4 buf[2][MAXPE];

    const int tid = threadIdx.x;
    const int nn  = N * N;
    const int pix = blockIdx.x * 256 + tid;
    const int a0  = blockIdx.y * chunk;
    const int cnt = min(A, a0 + chunk) - a0;

    const int x = pix % N;
    const int y = pix / N;
    const float half = (float)(N - 1) * 0.5f;
    const float cx = (float)x - half;
    const float cy = half - (float)y;
    const float q0 = trig[A].x;        // uniform -> s_load

    float acc0 = 0.f, acc1 = 0.f, acc2 = 0.f, acc3 = 0.f;

    stage_pe(packed + (size_t)a0 * PE, &buf[0][0], PE, tid);
    __syncthreads();

    for (int i = 0; i < cnt; ++i) {
        const int cur = i & 1;
        if (i + 1 < cnt)
            stage_pe(packed + (size_t)(a0 + i + 1) * PE, &buf[cur ^ 1][0], PE, tid);

        float2 t  = trig[a0 + i];      // uniform -> s_load_dwordx2
        float f   = fmaf(cx, t.x, fmaf(cy, t.y, q0));
        float i0f = floorf(f);
        int   i0  = (int)i0f;
        float w   = f - i0f;
        float m   = (i0 >= 0 && i0 <= P - 2) ? 1.0f : 0.0f;
        int   ic  = min(max(i0, 0), P - 2);
        float wm  = w * m;             // weight on v1
        float om  = m - wm;            // weight on v0

        uint4 e = buf[cur][ic];        // ds_read_b128: all 4 batches
        const __half2* hp = (const __half2*)&e;
        float2 g0 = __half22float2(hp[0]);
        float2 g1 = __half22float2(hp[1]);
        float2 g2 = __half22float2(hp[2]);
        float2 g3 = __half22float2(hp[3]);
        acc0 = fmaf(om, g0.x, fmaf(wm, g0.y, acc0));
        acc1 = fmaf(om, g1.x, fmaf(wm, g1.y, acc1));
        acc2 = fmaf(om, g2.x, fmaf(wm, g2.y, acc2));
        acc3 = fmaf(om, g3.x, fmaf(wm, g3.y, acc3));

        __syncthreads();               // buf[cur] reads done; prefetch landed
    }

    float* pp = part + (size_t)blockIdx.y * 4 * nn + pix;
    pp[0]              = acc0;
    pp[(size_t)nn]     = acc1;
    pp[(size_t)2 * nn] = acc2;
    pp[(size_t)3 * nn] = acc3;
}

__global__ __launch_bounds__(256) void radon_reduce_kernel(
    const float4* __restrict__ part,   // [nchunks][BN4] in float4
    float4* __restrict__ out,
    int BN4, int nchunks)
{
    int i = blockIdx.x * blockDim.x + threadIdx.x;
    if (i >= BN4) return;
    float4 s = make_float4(0.f, 0.f, 0.f, 0.f);
    for (int c = 0; c < nchunks; ++c) {
        float4 v = part[(size_t)c * BN4 + i];
        s.x += v.x; s.y += v.y; s.z += v.z; s.w += v.w;
    }
    out[i] = s;
}

// Generic fallback: direct per-batch kernel (any shape).
__global__ __launch_bounds__(256) void radon_direct_kernel(
    const float* __restrict__ sino,
    const float* __restrict__ thetas,
    const float* __restrict__ positions,
    float* __restrict__ out,
    int A, int P, int N, int BC)
{
    const int nn  = N * N;
    const int pix = blockIdx.x * blockDim.x + threadIdx.x;
    if (pix >= nn) return;
    const float p0     = positions[0];
    const float inv_dp = 1.0f / (positions[1] - p0);
    const int x = pix % N;
    const int y = pix / N;
    const float half = (float)(N - 1) * 0.5f;
    const float cx = (float)x - half;
    const float cy = half - (float)y;
    for (int b = 0; b < BC; ++b) {
        float acc = 0.0f;
        for (int a = 0; a < A; ++a) {
            float th = thetas[a];
            float f  = (cx * cosf(th) + cy * sinf(th) - p0) * inv_dp;
            float i0f = floorf(f);
            int i0 = (int)i0f;
            float w = f - i0f;
            float m = (i0 >= 0 && i0 <= P - 2) ? 1.0f : 0.0f;
            int ic = min(max(i0, 0), P - 2);
            const float* row = sino + ((size_t)b * A + a) * P + ic;
            acc = fmaf(m, fmaf(w, row[1] - row[0], row[0]), acc);
        }
        out[(size_t)b * nn + pix] = acc;
    }
}

extern "C" void kernel_launch(void* const* d_in, const int* in_sizes, int n_in,
                              void* d_out, int out_size, void* d_ws, size_t ws_size,
                              hipStream_t stream) {
    const float* sino      = (const float*)d_in[0];
    const float* thetas    = (const float*)d_in[1];
    const float* positions = (const float*)d_in[2];
    float* out             = (float*)d_out;

    const int A  = in_sizes[1];               // 180
    const int P  = in_sizes[2];               // 384
    const int BC = in_sizes[0] / (A * P);     // B*C = 4
    const int N  = (int)lroundf(sqrtf((float)(out_size / BC)));
    const int nn = N * N;
    const int bstride = A * P;

    const int PE    = (P + 63) & ~63;         // whole-wave staging
    const int chunk = (A + ACHUNKS - 1) / ACHUNKS;

    const size_t part_bytes   = (size_t)ACHUNKS * 4 * nn * sizeof(float);
    const size_t packed_bytes = (size_t)A * PE * sizeof(uint4);
    const size_t trig_bytes   = (size_t)(A + 1) * sizeof(float2);
    const size_t need = part_bytes + packed_bytes + trig_bytes;

    const bool fast = (BC == 4) && (A <= 256) && (P >= 2) && (PE <= MAXPE)
                   && (N % 64 == 0) && ((nn & 255) == 0) && (ws_size >= need);

    if (fast) {
        float*  part   = (float*)d_ws;
        uint4*  packed = (uint4*)((char*)d_ws + part_bytes);
        float2* trig   = (float2*)((char*)d_ws + part_bytes + packed_bytes);

        dim3 block(256);
        dim3 gpack(((unsigned)(A * PE) + 255) / 256);
        radon_pack<<<gpack, block, 0, stream>>>(
            sino, thetas, positions, packed, trig, A, P, PE, bstride);

        dim3 gpart(nn / 256, ACHUNKS);
        radon_partial_pk<<<gpart, block, 0, stream>>>(
            packed, trig, part, A, P, PE, N, chunk);

        const int BN4 = 4 * nn / 4;           // = nn
        dim3 gred((BN4 + 255) / 256);
        radon_reduce_kernel<<<gred, block, 0, stream>>>(
            (const float4*)part, (float4*)out, BN4, ACHUNKS);
    } else {
        dim3 block(256);
        dim3 grid((nn + 255) / 256);
        radon_direct_kernel<<<grid, block, 0, stream>>>(
            sino, thetas, positions, out, A, P, N, BC);
    }
}

// Round 7
// 77.680 us; speedup vs baseline: 1.0811x; 1.0811x over previous
//
#include <hip/hip_runtime.h>
#include <hip/hip_fp16.h>
#include <cmath>

// Radon backprojection, three-phase, packed-fp16 DIRECT-GLOBAL gather.
//
// R6 post-mortem: LDS-staged packed gather was neutral vs 8-dword-gather
// versions. Suspect: per-angle __syncthreads forces s_waitcnt vmcnt(0)
// (compiler drains before s_barrier) -> ~300 cyc exposed per angle per
// block. R7: after the pack pre-pass ([A][PE] uint4, fp16 (v0,v1) pairs
// for 4 batches), gather each entry DIRECTLY from global: one
// global_load_dwordx4 per pixel-angle, no LDS, no barrier in the loop.
// Waves independent; unroll-4 keeps gathers in flight; L1 serves the 6KB
// row to all waves of a block.

#define ACHUNKS 8
#define MAXPE   512

__global__ __launch_bounds__(256) void radon_pack(
    const float* __restrict__ sino,
    const float* __restrict__ thetas,
    const float* __restrict__ positions,
    uint4* __restrict__ packed,        // [A][PE]
    float2* __restrict__ trig,         // [A+1]; trig[A].x = q0
    int A, int P, int PE, int bstride)
{
    const int idx = blockIdx.x * 256 + threadIdx.x;
    const int a = idx / PE;
    const int i = idx - a * PE;
    if (a >= A) return;

    const float p0     = positions[0];
    const float inv_dp = 1.0f / (positions[1] - p0);
    if (i == 0) {
        float th = thetas[a];
        trig[a] = make_float2(cosf(th) * inv_dp, sinf(th) * inv_dp);
        if (a == 0) trig[A] = make_float2(-p0 * inv_dp, 0.0f);
    }

    const int i0 = min(i, P - 1);
    const int i1 = min(i + 1, P - 1);
    const float* s = sino + (size_t)a * P;

    uint4 e;
    unsigned* ep = (unsigned*)&e;
#pragma unroll
    for (int b = 0; b < 4; ++b) {
        const float* sb = s + (size_t)b * bstride;
        __half2 h = __floats2half2_rn(sb[i0], sb[i1]);  // lo=v0, hi=v1
        ep[b] = *(const unsigned*)&h;
    }
    packed[(size_t)a * PE + i] = e;
}

__global__ __launch_bounds__(256) void radon_partial_gg(
    const uint4* __restrict__ packed,  // [A][PE]
    const float2* __restrict__ trig,   // [A+1]
    float* __restrict__ part,          // [ACHUNKS][4][nn]
    int A, int P, int PE, int N, int chunk)
{
    const int tid = threadIdx.x;
    const int nn  = N * N;
    const int pix = blockIdx.x * 256 + tid;
    const int a0  = blockIdx.y * chunk;
    const int cnt = min(A, a0 + chunk) - a0;

    const int x = pix % N;
    const int y = pix / N;
    const float half = (float)(N - 1) * 0.5f;
    const float cx = (float)x - half;
    const float cy = half - (float)y;
    const float q0 = trig[A].x;        // uniform -> s_load

    float acc0 = 0.f, acc1 = 0.f, acc2 = 0.f, acc3 = 0.f;

#pragma unroll 4
    for (int i = 0; i < cnt; ++i) {
        const int a = a0 + i;
        float2 t  = trig[a];           // uniform -> s_load_dwordx2
        float f   = fmaf(cx, t.x, fmaf(cy, t.y, q0));
        float i0f = floorf(f);
        int   i0  = (int)i0f;
        float w   = f - i0f;
        float m   = (i0 >= 0 && i0 <= P - 2) ? 1.0f : 0.0f;
        int   ic  = min(max(i0, 0), P - 2);
        float wm  = w * m;             // weight on v1
        float om  = m - wm;            // weight on v0

        uint4 e = packed[(size_t)a * PE + ic];   // global_load_dwordx4 gather
        const __half2* hp = (const __half2*)&e;
        float2 g0 = __half22float2(hp[0]);
        float2 g1 = __half22float2(hp[1]);
        float2 g2 = __half22float2(hp[2]);
        float2 g3 = __half22float2(hp[3]);
        acc0 = fmaf(om, g0.x, fmaf(wm, g0.y, acc0));
        acc1 = fmaf(om, g1.x, fmaf(wm, g1.y, acc1));
        acc2 = fmaf(om, g2.x, fmaf(wm, g2.y, acc2));
        acc3 = fmaf(om, g3.x, fmaf(wm, g3.y, acc3));
    }

    if (pix < nn) {
        float* pp = part + (size_t)blockIdx.y * 4 * nn + pix;
        pp[0]              = acc0;
        pp[(size_t)nn]     = acc1;
        pp[(size_t)2 * nn] = acc2;
        pp[(size_t)3 * nn] = acc3;
    }
}

__global__ __launch_bounds__(256) void radon_reduce_kernel(
    const float4* __restrict__ part,   // [nchunks][BN4] in float4
    float4* __restrict__ out,
    int BN4, int nchunks)
{
    int i = blockIdx.x * blockDim.x + threadIdx.x;
    if (i >= BN4) return;
    float4 s = make_float4(0.f, 0.f, 0.f, 0.f);
    for (int c = 0; c < nchunks; ++c) {
        float4 v = part[(size_t)c * BN4 + i];
        s.x += v.x; s.y += v.y; s.z += v.z; s.w += v.w;
    }
    out[i] = s;
}

// Generic fallback: direct per-batch kernel (any shape).
__global__ __launch_bounds__(256) void radon_direct_kernel(
    const float* __restrict__ sino,
    const float* __restrict__ thetas,
    const float* __restrict__ positions,
    float* __restrict__ out,
    int A, int P, int N, int BC)
{
    const int nn  = N * N;
    const int pix = blockIdx.x * blockDim.x + threadIdx.x;
    if (pix >= nn) return;
    const float p0     = positions[0];
    const float inv_dp = 1.0f / (positions[1] - p0);
    const int x = pix % N;
    const int y = pix / N;
    const float half = (float)(N - 1) * 0.5f;
    const float cx = (float)x - half;
    const float cy = half - (float)y;
    for (int b = 0; b < BC; ++b) {
        float acc = 0.0f;
        for (int a = 0; a < A; ++a) {
            float th = thetas[a];
            float f  = (cx * cosf(th) + cy * sinf(th) - p0) * inv_dp;
            float i0f = floorf(f);
            int i0 = (int)i0f;
            float w = f - i0f;
            float m = (i0 >= 0 && i0 <= P - 2) ? 1.0f : 0.0f;
            int ic = min(max(i0, 0), P - 2);
            const float* row = sino + ((size_t)b * A + a) * P + ic;
            acc = fmaf(m, fmaf(w, row[1] - row[0], row[0]), acc);
        }
        out[(size_t)b * nn + pix] = acc;
    }
}

extern "C" void kernel_launch(void* const* d_in, const int* in_sizes, int n_in,
                              void* d_out, int out_size, void* d_ws, size_t ws_size,
                              hipStream_t stream) {
    const float* sino      = (const float*)d_in[0];
    const float* thetas    = (const float*)d_in[1];
    const float* positions = (const float*)d_in[2];
    float* out             = (float*)d_out;

    const int A  = in_sizes[1];               // 180
    const int P  = in_sizes[2];               // 384
    const int BC = in_sizes[0] / (A * P);     // B*C = 4
    const int N  = (int)lroundf(sqrtf((float)(out_size / BC)));
    const int nn = N * N;
    const int bstride = A * P;

    const int PE    = (P + 63) & ~63;
    const int chunk = (A + ACHUNKS - 1) / ACHUNKS;

    const size_t part_bytes   = (size_t)ACHUNKS * 4 * nn * sizeof(float);
    const size_t packed_bytes = (size_t)A * PE * sizeof(uint4);
    const size_t trig_bytes   = (size_t)(A + 1) * sizeof(float2);
    const size_t need = part_bytes + packed_bytes + trig_bytes;

    const bool fast = (BC == 4) && (A <= 256) && (P >= 2) && (PE <= MAXPE)
                   && (N % 64 == 0) && ((nn & 255) == 0) && (ws_size >= need);

    if (fast) {
        float*  part   = (float*)d_ws;
        uint4*  packed = (uint4*)((char*)d_ws + part_bytes);
        float2* trig   = (float2*)((char*)d_ws + part_bytes + packed_bytes);

        dim3 block(256);
        dim3 gpack(((unsigned)(A * PE) + 255) / 256);
        radon_pack<<<gpack, block, 0, stream>>>(
            sino, thetas, positions, packed, trig, A, P, PE, bstride);

        dim3 gpart(nn / 256, ACHUNKS);
        radon_partial_gg<<<gpart, block, 0, stream>>>(
            packed, trig, part, A, P, PE, N, chunk);

        const int BN4 = 4 * nn / 4;           // = nn
        dim3 gred((BN4 + 255) / 256);
        radon_reduce_kernel<<<gred, block, 0, stream>>>(
            (const float4*)part, (float4*)out, BN4, ACHUNKS);
    } else {
        dim3 block(256);
        dim3 grid((nn + 255) / 256);
        radon_direct_kernel<<<grid, block, 0, stream>>>(
            sino, thetas, positions, out, A, P, N, BC);
    }
}